// Round 1
// baseline (541.189 us; speedup 1.0000x reference)
//
#include <hip/hip_runtime.h>

#define N_NODES 50000
#define N_EDGES 800000
#define D 128
#define N_LABELS 4096

// ---------------------------------------------------------------------------
// CSR build
// ---------------------------------------------------------------------------

__global__ void count_kernel(const int* __restrict__ src, const int* __restrict__ dst,
                             int* __restrict__ cnt_out, int* __restrict__ cnt_in) {
    int e = blockIdx.x * 256 + threadIdx.x;
    if (e >= N_EDGES) return;
    atomicAdd(&cnt_out[src[e]], 1);
    atomicAdd(&cnt_in[dst[e]], 1);
}

__global__ void dinv_kernel(const int* __restrict__ cnt_out, const int* __restrict__ cnt_in,
                            float* __restrict__ dinv_out, float* __restrict__ dinv_in) {
    int n = blockIdx.x * 256 + threadIdx.x;
    if (n >= N_NODES) return;
    int co = cnt_out[n], ci = cnt_in[n];
    dinv_out[n] = (co > 0) ? 1.0f / sqrtf((float)co) : 0.0f;
    dinv_in[n]  = (ci > 0) ? 1.0f / sqrtf((float)ci) : 0.0f;
}

// inclusive scan of cnt_in in 256-element blocks; row_off[i+1] gets partial scans
__global__ void scan_blocks_kernel(const int* __restrict__ cnt, int* __restrict__ row_off,
                                   int* __restrict__ blocksums) {
    __shared__ int s[256];
    int t = threadIdx.x;
    int i = blockIdx.x * 256 + t;
    int v = (i < N_NODES) ? cnt[i] : 0;
    s[t] = v;
    __syncthreads();
    for (int offs = 1; offs < 256; offs <<= 1) {
        int add = (t >= offs) ? s[t - offs] : 0;
        __syncthreads();
        s[t] += add;
        __syncthreads();
    }
    if (i < N_NODES) row_off[i + 1] = s[t];
    if (t == 255) blocksums[blockIdx.x] = s[255];
}

__global__ void scan_top_kernel(const int* __restrict__ blocksums, int* __restrict__ blockoffs,
                                int nblocks) {
    __shared__ int s[256];
    int t = threadIdx.x;
    int v = (t < nblocks) ? blocksums[t] : 0;
    s[t] = v;
    __syncthreads();
    for (int offs = 1; offs < 256; offs <<= 1) {
        int add = (t >= offs) ? s[t - offs] : 0;
        __syncthreads();
        s[t] += add;
        __syncthreads();
    }
    blockoffs[t] = s[t] - v;  // exclusive scan
}

__global__ void scan_add_kernel(int* __restrict__ row_off, const int* __restrict__ blockoffs) {
    int i = blockIdx.x * 256 + threadIdx.x;
    if (i < N_NODES) row_off[i + 1] += blockoffs[blockIdx.x];
    if (i == 0) row_off[0] = 0;
}

__global__ void fill_csr_kernel(const int* __restrict__ src, const int* __restrict__ dst,
                                const int* __restrict__ row_off, int* __restrict__ cursor,
                                int* __restrict__ csr_src) {
    int e = blockIdx.x * 256 + threadIdx.x;
    if (e >= N_EDGES) return;
    int d = dst[e];
    int p = atomicAdd(&cursor[d], 1);
    csr_src[row_off[d] + p] = src[e];
}

// ---------------------------------------------------------------------------
// Pull aggregation: out[n] = dinv_in[n] * sum_{s in N_in(n)} dinv_out[s] * h[s]
// one wave per node; lane holds float2 slice of the 128-dim row
// ---------------------------------------------------------------------------

__global__ __launch_bounds__(256) void aggregate_kernel(
        const float* __restrict__ h, const int* __restrict__ csr_src,
        const int* __restrict__ row_off, const float* __restrict__ dinv_out,
        const float* __restrict__ dinv_in, float* __restrict__ outbuf) {
    int wave = threadIdx.x >> 6;
    int lane = threadIdx.x & 63;
    int n = blockIdx.x * 4 + wave;
    if (n >= N_NODES) return;
    int start = row_off[n];
    int end = row_off[n + 1];
    const float2* h2 = (const float2*)h;
    float ax = 0.f, ay = 0.f;
    for (int j0 = start; j0 < end; j0 += 64) {
        int jj = j0 + lane;
        int sv = (jj < end) ? csr_src[jj] : 0;
        int nj = min(64, end - j0);
        for (int i = 0; i < nj; ++i) {
            int s = __shfl(sv, i, 64);
            float w = dinv_out[s];
            float2 hv = h2[(size_t)s * 64 + lane];
            ax = fmaf(w, hv.x, ax);
            ay = fmaf(w, hv.y, ay);
        }
    }
    float wi = dinv_in[n];
    float2 r;
    r.x = ax * wi;
    r.y = ay * wi;
    ((float2*)outbuf)[(size_t)n * 64 + lane] = r;
}

// ---------------------------------------------------------------------------
// out[n][c] = sum_k in[n][k] * W[k][c] + b[c]   (f32 vector FMA, W in LDS)
// ---------------------------------------------------------------------------

__global__ __launch_bounds__(256) void matmul_bias_kernel(
        const float* __restrict__ in, const float* __restrict__ W,
        const float* __restrict__ b, float* __restrict__ outbuf) {
    __shared__ float Ws[D * D];
    __shared__ float rows[8][D];
    __shared__ float bs[D];
    int t = threadIdx.x;
    for (int i = t; i < D * D; i += 256) Ws[i] = W[i];
    if (t < D) bs[t] = b[t];
    __syncthreads();
    int c = t & 127;
    int rg = t >> 7;  // 0 or 1
    int ntiles = (N_NODES + 7) / 8;
    for (int tile = blockIdx.x; tile < ntiles; tile += gridDim.x) {
        int r0 = tile * 8;
        for (int i = t; i < 8 * D; i += 256) {
            int rr = i >> 7, cc = i & 127;
            int r = r0 + rr;
            rows[rr][cc] = (r < N_NODES) ? in[(size_t)r * D + cc] : 0.f;
        }
        __syncthreads();
        for (int rr = rg; rr < 8; rr += 2) {
            int r = r0 + rr;
            if (r < N_NODES) {
                float acc = bs[c];
#pragma unroll
                for (int k = 0; k < D; ++k) acc = fmaf(rows[rr][k], Ws[k * D + c], acc);
                outbuf[(size_t)r * D + c] = acc;
            }
        }
        __syncthreads();
    }
}

// ---------------------------------------------------------------------------
// final gather: out[i] = h[labels[i]]
// ---------------------------------------------------------------------------

__global__ void gather_labels_kernel(const float* __restrict__ h, const int* __restrict__ labels,
                                     float* __restrict__ outp) {
    int i = blockIdx.x * 256 + threadIdx.x;  // float4 index
    if (i >= N_LABELS * 32) return;
    int li = i >> 5, q = i & 31;
    int n = labels[li];
    ((float4*)outp)[i] = ((const float4*)h)[(size_t)n * 32 + q];
}

// ---------------------------------------------------------------------------

extern "C" void kernel_launch(void* const* d_in, const int* in_sizes, int n_in,
                              void* d_out, int out_size, void* d_ws, size_t ws_size,
                              hipStream_t stream) {
    const int* labels = (const int*)d_in[0];
    const int* src    = (const int*)d_in[1];
    const int* dst    = (const int*)d_in[2];
    const float* feat = (const float*)d_in[3];
    const float* W0   = (const float*)d_in[4];
    const float* b0   = (const float*)d_in[5];
    const float* W1   = (const float*)d_in[6];
    const float* b1   = (const float*)d_in[7];
    const float* W2   = (const float*)d_in[8];
    const float* b2   = (const float*)d_in[9];
    float* out = (float*)d_out;

    char* ws = (char*)d_ws;
    size_t off = 0;
    auto alloc = [&](size_t bytes) -> void* {
        void* p = ws + off;
        off = (off + bytes + 255) & ~(size_t)255;
        return p;
    };
    int* cnt_out   = (int*)alloc(N_NODES * 4);
    int* cnt_in    = (int*)alloc(N_NODES * 4);
    int* row_off   = (int*)alloc((N_NODES + 1) * 4);
    int* cursor    = (int*)alloc(N_NODES * 4);
    int* blocksums = (int*)alloc(256 * 4);
    int* blockoffs = (int*)alloc(256 * 4);
    int* csr_src   = (int*)alloc((size_t)N_EDGES * 4);
    float* dinv_out = (float*)alloc(N_NODES * 4);
    float* dinv_in  = (float*)alloc(N_NODES * 4);
    float* bufA = (float*)alloc((size_t)N_NODES * D * 4);
    float* bufB = (float*)alloc((size_t)N_NODES * D * 4);

    hipMemsetAsync(cnt_out, 0, N_NODES * 4, stream);
    hipMemsetAsync(cnt_in, 0, N_NODES * 4, stream);
    hipMemsetAsync(cursor, 0, N_NODES * 4, stream);

    const int nScanBlocks = (N_NODES + 255) / 256;  // 196

    count_kernel<<<(N_EDGES + 255) / 256, 256, 0, stream>>>(src, dst, cnt_out, cnt_in);
    dinv_kernel<<<nScanBlocks, 256, 0, stream>>>(cnt_out, cnt_in, dinv_out, dinv_in);
    scan_blocks_kernel<<<nScanBlocks, 256, 0, stream>>>(cnt_in, row_off, blocksums);
    scan_top_kernel<<<1, 256, 0, stream>>>(blocksums, blockoffs, nScanBlocks);
    scan_add_kernel<<<nScanBlocks, 256, 0, stream>>>(row_off, blockoffs);
    fill_csr_kernel<<<(N_EDGES + 255) / 256, 256, 0, stream>>>(src, dst, row_off, cursor, csr_src);

    const int aggGrid = (N_NODES + 3) / 4;  // 1 wave per node, 4 waves/block
    const int mmGrid = 800;

    // layer 0
    aggregate_kernel<<<aggGrid, 256, 0, stream>>>(feat, csr_src, row_off, dinv_out, dinv_in, bufB);
    matmul_bias_kernel<<<mmGrid, 256, 0, stream>>>(bufB, W0, b0, bufA);
    // layer 1
    aggregate_kernel<<<aggGrid, 256, 0, stream>>>(bufA, csr_src, row_off, dinv_out, dinv_in, bufB);
    matmul_bias_kernel<<<mmGrid, 256, 0, stream>>>(bufB, W1, b1, bufA);
    // layer 2
    aggregate_kernel<<<aggGrid, 256, 0, stream>>>(bufA, csr_src, row_off, dinv_out, dinv_in, bufB);
    matmul_bias_kernel<<<mmGrid, 256, 0, stream>>>(bufB, W2, b2, bufA);

    gather_labels_kernel<<<(N_LABELS * 32 + 255) / 256, 256, 0, stream>>>(bufA, labels, out);
}

// Round 2
// 393.949 us; speedup vs baseline: 1.3738x; 1.3738x over previous
//
#include <hip/hip_runtime.h>

#define N_NODES 50000
#define N_EDGES 800000
#define D 128
#define N_LABELS 4096
#define MM_TILE 64

// ---------------------------------------------------------------------------
// CSR build
// ---------------------------------------------------------------------------

__global__ void count_kernel(const int* __restrict__ src, const int* __restrict__ dst,
                             int* __restrict__ cnt_out, int* __restrict__ cnt_in) {
    int e = blockIdx.x * 256 + threadIdx.x;
    if (e >= N_EDGES) return;
    atomicAdd(&cnt_out[src[e]], 1);
    atomicAdd(&cnt_in[dst[e]], 1);
}

__global__ void dinv_kernel(const int* __restrict__ cnt_out, const int* __restrict__ cnt_in,
                            float* __restrict__ dinv_out, float* __restrict__ dinv_in) {
    int n = blockIdx.x * 256 + threadIdx.x;
    if (n >= N_NODES) return;
    int co = cnt_out[n], ci = cnt_in[n];
    dinv_out[n] = (co > 0) ? 1.0f / sqrtf((float)co) : 0.0f;
    dinv_in[n]  = (ci > 0) ? 1.0f / sqrtf((float)ci) : 0.0f;
}

__global__ void scan_blocks_kernel(const int* __restrict__ cnt, int* __restrict__ row_off,
                                   int* __restrict__ blocksums) {
    __shared__ int s[256];
    int t = threadIdx.x;
    int i = blockIdx.x * 256 + t;
    int v = (i < N_NODES) ? cnt[i] : 0;
    s[t] = v;
    __syncthreads();
    for (int offs = 1; offs < 256; offs <<= 1) {
        int add = (t >= offs) ? s[t - offs] : 0;
        __syncthreads();
        s[t] += add;
        __syncthreads();
    }
    if (i < N_NODES) row_off[i + 1] = s[t];
    if (t == 255) blocksums[blockIdx.x] = s[255];
}

__global__ void scan_top_kernel(const int* __restrict__ blocksums, int* __restrict__ blockoffs,
                                int nblocks) {
    __shared__ int s[256];
    int t = threadIdx.x;
    int v = (t < nblocks) ? blocksums[t] : 0;
    s[t] = v;
    __syncthreads();
    for (int offs = 1; offs < 256; offs <<= 1) {
        int add = (t >= offs) ? s[t - offs] : 0;
        __syncthreads();
        s[t] += add;
        __syncthreads();
    }
    blockoffs[t] = s[t] - v;  // exclusive
}

__global__ void scan_add_kernel(int* __restrict__ row_off, const int* __restrict__ blockoffs) {
    int i = blockIdx.x * 256 + threadIdx.x;
    if (i < N_NODES) row_off[i + 1] += blockoffs[blockIdx.x];
    if (i == 0) row_off[0] = 0;
}

__global__ void fill_csr_kernel(const int* __restrict__ src, const int* __restrict__ dst,
                                const int* __restrict__ row_off, int* __restrict__ cursor,
                                int* __restrict__ csr_src) {
    int e = blockIdx.x * 256 + threadIdx.x;
    if (e >= N_EDGES) return;
    int d = dst[e];
    int p = atomicAdd(&cursor[d], 1);
    csr_src[row_off[d] + p] = src[e];
}

// ---------------------------------------------------------------------------
// prescale: hs = feat * dinv_out[n]
// ---------------------------------------------------------------------------

__global__ void prescale_kernel(const float* __restrict__ feat,
                                const float* __restrict__ dinv_out,
                                float* __restrict__ hs) {
    int i = blockIdx.x * 256 + threadIdx.x;  // float4 index
    if (i >= N_NODES * 32) return;
    int n = i >> 5;
    float s = dinv_out[n];
    float4 v = ((const float4*)feat)[i];
    float4 r;
    r.x = v.x * s; r.y = v.y * s; r.z = v.z * s; r.w = v.w * s;
    ((float4*)hs)[i] = r;
}

// ---------------------------------------------------------------------------
// Pull aggregation over pre-scaled hs:
//   out[row] = dinv_in[n] * sum_{s in N_in(n)} hs[s],  n = nodeidx ? nodeidx[row] : row
// one wave per row; each half-wave (32 lanes, float4/lane) takes alternate neighbors
// ---------------------------------------------------------------------------

__global__ __launch_bounds__(256) void aggregate_kernel(
        const float* __restrict__ hs, const int* __restrict__ csr_src,
        const int* __restrict__ row_off, const float* __restrict__ dinv_in,
        float* __restrict__ outbuf, const int* __restrict__ nodeidx, int nrows) {
    int wave = threadIdx.x >> 6;
    int lane = threadIdx.x & 63;
    int hw = lane >> 5, l32 = lane & 31;
    int row = blockIdx.x * 4 + wave;
    if (row >= nrows) return;
    int n = nodeidx ? nodeidx[row] : row;
    int start = row_off[n];
    int end = row_off[n + 1];
    const float4* h4 = (const float4*)hs;
    float4 acc = make_float4(0.f, 0.f, 0.f, 0.f);
    for (int j0 = start; j0 < end; j0 += 64) {
        int jj = j0 + lane;
        int sv = (jj < end) ? csr_src[jj] : 0;
        int nj = min(64, end - j0);
#pragma unroll 4
        for (int i = 0; i < nj; i += 2) {
            int idx = i + hw;
            int s = __shfl(sv, idx, 64);
            if (idx < nj) {
                float4 hv = h4[(size_t)s * 32 + l32];
                acc.x += hv.x; acc.y += hv.y; acc.z += hv.z; acc.w += hv.w;
            }
        }
    }
    // combine the two halves (even/odd neighbor partial sums)
    acc.x += __shfl_xor(acc.x, 32, 64);
    acc.y += __shfl_xor(acc.y, 32, 64);
    acc.z += __shfl_xor(acc.z, 32, 64);
    acc.w += __shfl_xor(acc.w, 32, 64);
    if (hw == 0) {
        float wi = dinv_in[n];
        float4 r;
        r.x = acc.x * wi; r.y = acc.y * wi; r.z = acc.z * wi; r.w = acc.w * wi;
        ((float4*)outbuf)[(size_t)row * 32 + l32] = r;
    }
}

// ---------------------------------------------------------------------------
// Register-blocked matmul: out[r][c] = (sum_k in[r][k]*W[k][c] + b[c]) * scale[r]
// block = 256 threads, tile = 64 rows x 128 cols; thread = 4 rows x 8 cols
// ---------------------------------------------------------------------------

#define FMA_ROW(i, aval, w0, w1)                                                  \
    acc[i][0] = fmaf(aval, w0.x, acc[i][0]); acc[i][1] = fmaf(aval, w0.y, acc[i][1]); \
    acc[i][2] = fmaf(aval, w0.z, acc[i][2]); acc[i][3] = fmaf(aval, w0.w, acc[i][3]); \
    acc[i][4] = fmaf(aval, w1.x, acc[i][4]); acc[i][5] = fmaf(aval, w1.y, acc[i][5]); \
    acc[i][6] = fmaf(aval, w1.z, acc[i][6]); acc[i][7] = fmaf(aval, w1.w, acc[i][7]);

#define KK_STEP(comp)                                                \
    {                                                                \
        float4 w0 = *(const float4*)&Ws[kw * D + tx * 8];            \
        float4 w1 = *(const float4*)&Ws[kw * D + tx * 8 + 4];        \
        FMA_ROW(0, a0.comp, w0, w1)                                  \
        FMA_ROW(1, a1.comp, w0, w1)                                  \
        FMA_ROW(2, a2.comp, w0, w1)                                  \
        FMA_ROW(3, a3.comp, w0, w1)                                  \
        kw++;                                                        \
    }

__global__ __launch_bounds__(256) void matmul_bias_kernel(
        const float* __restrict__ in, const float* __restrict__ W,
        const float* __restrict__ b, const float* __restrict__ scale,
        float* __restrict__ outbuf, int nrows) {
    __shared__ float Ws[D * D];             // 64 KB
    __shared__ float As[MM_TILE][D + 4];    // 64 x 132 f32 = 33.8 KB, pad keeps reads 2-way (free)
    int t = threadIdx.x;
    int tx = t & 15, ty = t >> 4;

    for (int i = t; i < D * D / 4; i += 256)
        ((float4*)Ws)[i] = ((const float4*)W)[i];

    float4 bv0 = ((const float4*)b)[tx * 2];
    float4 bv1 = ((const float4*)b)[tx * 2 + 1];

    int r0 = blockIdx.x * MM_TILE;
    for (int i = t; i < MM_TILE * 32; i += 256) {  // 2048 float4
        int rr = i >> 5, kq = i & 31;
        float4 v = make_float4(0.f, 0.f, 0.f, 0.f);
        if (r0 + rr < nrows) v = ((const float4*)in)[(size_t)(r0 + rr) * 32 + kq];
        *(float4*)&As[rr][kq * 4] = v;
    }
    __syncthreads();

    float acc[4][8];
#pragma unroll
    for (int i = 0; i < 4; ++i) {
        acc[i][0] = bv0.x; acc[i][1] = bv0.y; acc[i][2] = bv0.z; acc[i][3] = bv0.w;
        acc[i][4] = bv1.x; acc[i][5] = bv1.y; acc[i][6] = bv1.z; acc[i][7] = bv1.w;
    }

    int rbase = ty * 4;
#pragma unroll 4
    for (int k = 0; k < D; k += 4) {
        float4 a0 = *(const float4*)&As[rbase + 0][k];
        float4 a1 = *(const float4*)&As[rbase + 1][k];
        float4 a2 = *(const float4*)&As[rbase + 2][k];
        float4 a3 = *(const float4*)&As[rbase + 3][k];
        int kw = k;
        KK_STEP(x)
        KK_STEP(y)
        KK_STEP(z)
        KK_STEP(w)
    }

#pragma unroll
    for (int i = 0; i < 4; ++i) {
        int r = r0 + rbase + i;
        if (r < nrows) {
            float s = scale ? scale[r] : 1.0f;
            float4 o0, o1;
            o0.x = acc[i][0] * s; o0.y = acc[i][1] * s; o0.z = acc[i][2] * s; o0.w = acc[i][3] * s;
            o1.x = acc[i][4] * s; o1.y = acc[i][5] * s; o1.z = acc[i][6] * s; o1.w = acc[i][7] * s;
            float4* op = (float4*)&outbuf[(size_t)r * D + tx * 8];
            op[0] = o0;
            op[1] = o1;
        }
    }
}

// ---------------------------------------------------------------------------

extern "C" void kernel_launch(void* const* d_in, const int* in_sizes, int n_in,
                              void* d_out, int out_size, void* d_ws, size_t ws_size,
                              hipStream_t stream) {
    const int* labels = (const int*)d_in[0];
    const int* src    = (const int*)d_in[1];
    const int* dst    = (const int*)d_in[2];
    const float* feat = (const float*)d_in[3];
    const float* W0   = (const float*)d_in[4];
    const float* b0   = (const float*)d_in[5];
    const float* W1   = (const float*)d_in[6];
    const float* b1   = (const float*)d_in[7];
    const float* W2   = (const float*)d_in[8];
    const float* b2   = (const float*)d_in[9];
    float* out = (float*)d_out;

    char* ws = (char*)d_ws;
    size_t off = 0;
    auto alloc = [&](size_t bytes) -> void* {
        void* p = ws + off;
        off = (off + bytes + 255) & ~(size_t)255;
        return p;
    };
    int* cnt_out   = (int*)alloc(N_NODES * 4);
    int* cnt_in    = (int*)alloc(N_NODES * 4);
    int* row_off   = (int*)alloc((N_NODES + 1) * 4);
    int* cursor    = (int*)alloc(N_NODES * 4);
    int* blocksums = (int*)alloc(256 * 4);
    int* blockoffs = (int*)alloc(256 * 4);
    int* csr_src   = (int*)alloc((size_t)N_EDGES * 4);
    float* dinv_out = (float*)alloc(N_NODES * 4);
    float* dinv_in  = (float*)alloc(N_NODES * 4);
    float* bufA = (float*)alloc((size_t)N_NODES * D * 4);
    float* bufB = (float*)alloc((size_t)N_NODES * D * 4);

    hipMemsetAsync(cnt_out, 0, N_NODES * 4, stream);
    hipMemsetAsync(cnt_in, 0, N_NODES * 4, stream);
    hipMemsetAsync(cursor, 0, N_NODES * 4, stream);

    const int nScanBlocks = (N_NODES + 255) / 256;  // 196

    count_kernel<<<(N_EDGES + 255) / 256, 256, 0, stream>>>(src, dst, cnt_out, cnt_in);
    dinv_kernel<<<nScanBlocks, 256, 0, stream>>>(cnt_out, cnt_in, dinv_out, dinv_in);
    scan_blocks_kernel<<<nScanBlocks, 256, 0, stream>>>(cnt_in, row_off, blocksums);
    scan_top_kernel<<<1, 256, 0, stream>>>(blocksums, blockoffs, nScanBlocks);
    scan_add_kernel<<<nScanBlocks, 256, 0, stream>>>(row_off, blockoffs);
    fill_csr_kernel<<<(N_EDGES + 255) / 256, 256, 0, stream>>>(src, dst, row_off, cursor, csr_src);

    const int aggGridFull = (N_NODES + 3) / 4;
    const int aggGridLbl  = (N_LABELS + 3) / 4;
    const int mmGridFull  = (N_NODES + MM_TILE - 1) / MM_TILE;  // 782
    const int mmGridLbl   = (N_LABELS + MM_TILE - 1) / MM_TILE; // 64

    // hs0 = feat * dinv_out  -> bufA
    prescale_kernel<<<(N_NODES * 32 + 255) / 256, 256, 0, stream>>>(feat, dinv_out, bufA);

    // layer 0: agg(bufA) -> bufB ; (bufB@W0+b0)*dinv_out -> bufA
    aggregate_kernel<<<aggGridFull, 256, 0, stream>>>(bufA, csr_src, row_off, dinv_in, bufB,
                                                      nullptr, N_NODES);
    matmul_bias_kernel<<<mmGridFull, 256, 0, stream>>>(bufB, W0, b0, dinv_out, bufA, N_NODES);

    // layer 1
    aggregate_kernel<<<aggGridFull, 256, 0, stream>>>(bufA, csr_src, row_off, dinv_in, bufB,
                                                      nullptr, N_NODES);
    matmul_bias_kernel<<<mmGridFull, 256, 0, stream>>>(bufB, W1, b1, dinv_out, bufA, N_NODES);

    // layer 2: only label rows
    aggregate_kernel<<<aggGridLbl, 256, 0, stream>>>(bufA, csr_src, row_off, dinv_in, bufB,
                                                     labels, N_LABELS);
    matmul_bias_kernel<<<mmGridLbl, 256, 0, stream>>>(bufB, W2, b2, nullptr, out, N_LABELS);
}

// Round 3
// 389.717 us; speedup vs baseline: 1.3887x; 1.0109x over previous
//
#include <hip/hip_runtime.h>

#define N_NODES 50000
#define N_EDGES 800000
#define D 128
#define N_LABELS 4096

// ---------------------------------------------------------------------------
// CSR build
// ---------------------------------------------------------------------------

__global__ void count_kernel(const int* __restrict__ src, const int* __restrict__ dst,
                             int* __restrict__ cnt_out, int* __restrict__ cnt_in) {
    int e = blockIdx.x * 256 + threadIdx.x;
    if (e >= N_EDGES) return;
    atomicAdd(&cnt_out[src[e]], 1);
    atomicAdd(&cnt_in[dst[e]], 1);
}

__global__ void dinv_kernel(const int* __restrict__ cnt_out, const int* __restrict__ cnt_in,
                            float* __restrict__ dinv_out, float* __restrict__ dinv_in) {
    int n = blockIdx.x * 256 + threadIdx.x;
    if (n >= N_NODES) return;
    int co = cnt_out[n], ci = cnt_in[n];
    dinv_out[n] = (co > 0) ? 1.0f / sqrtf((float)co) : 0.0f;
    dinv_in[n]  = (ci > 0) ? 1.0f / sqrtf((float)ci) : 0.0f;
}

__global__ void scan_blocks_kernel(const int* __restrict__ cnt, int* __restrict__ row_off,
                                   int* __restrict__ blocksums) {
    __shared__ int s[256];
    int t = threadIdx.x;
    int i = blockIdx.x * 256 + t;
    int v = (i < N_NODES) ? cnt[i] : 0;
    s[t] = v;
    __syncthreads();
    for (int offs = 1; offs < 256; offs <<= 1) {
        int add = (t >= offs) ? s[t - offs] : 0;
        __syncthreads();
        s[t] += add;
        __syncthreads();
    }
    if (i < N_NODES) row_off[i + 1] = s[t];
    if (t == 255) blocksums[blockIdx.x] = s[255];
}

__global__ void scan_top_kernel(const int* __restrict__ blocksums, int* __restrict__ blockoffs,
                                int nblocks) {
    __shared__ int s[256];
    int t = threadIdx.x;
    int v = (t < nblocks) ? blocksums[t] : 0;
    s[t] = v;
    __syncthreads();
    for (int offs = 1; offs < 256; offs <<= 1) {
        int add = (t >= offs) ? s[t - offs] : 0;
        __syncthreads();
        s[t] += add;
        __syncthreads();
    }
    blockoffs[t] = s[t] - v;  // exclusive
}

__global__ void scan_add_kernel(int* __restrict__ row_off, const int* __restrict__ blockoffs) {
    int i = blockIdx.x * 256 + threadIdx.x;
    if (i < N_NODES) row_off[i + 1] += blockoffs[blockIdx.x];
    if (i == 0) row_off[0] = 0;
}

__global__ void fill_csr_kernel(const int* __restrict__ src, const int* __restrict__ dst,
                                const int* __restrict__ row_off, int* __restrict__ cursor,
                                int* __restrict__ csr_src) {
    int e = blockIdx.x * 256 + threadIdx.x;
    if (e >= N_EDGES) return;
    int d = dst[e];
    int p = atomicAdd(&cursor[d], 1);
    csr_src[row_off[d] + p] = src[e];
}

// ---------------------------------------------------------------------------
// prescale: hs = feat * dinv_out[n]
// ---------------------------------------------------------------------------

__global__ void prescale_kernel(const float* __restrict__ feat,
                                const float* __restrict__ dinv_out,
                                float* __restrict__ hs) {
    int i = blockIdx.x * 256 + threadIdx.x;  // float4 index
    if (i >= N_NODES * 32) return;
    int n = i >> 5;
    float s = dinv_out[n];
    float4 v = ((const float4*)feat)[i];
    float4 r;
    r.x = v.x * s; r.y = v.y * s; r.z = v.z * s; r.w = v.w * s;
    ((float4*)hs)[i] = r;
}

// ---------------------------------------------------------------------------
// Pull aggregation over pre-scaled hs:
//   out[row] = dinv_in[n] * sum_{s in N_in(n)} hs[s],  n = nodeidx ? nodeidx[row] : row
// one wave per row; each half-wave (32 lanes, float4/lane) takes alternate neighbors
// ---------------------------------------------------------------------------

__global__ __launch_bounds__(256) void aggregate_kernel(
        const float* __restrict__ hs, const int* __restrict__ csr_src,
        const int* __restrict__ row_off, const float* __restrict__ dinv_in,
        float* __restrict__ outbuf, const int* __restrict__ nodeidx, int nrows) {
    int wave = threadIdx.x >> 6;
    int lane = threadIdx.x & 63;
    int hw = lane >> 5, l32 = lane & 31;
    int row = blockIdx.x * 4 + wave;
    if (row >= nrows) return;
    int n = nodeidx ? nodeidx[row] : row;
    int start = row_off[n];
    int end = row_off[n + 1];
    const float4* h4 = (const float4*)hs;
    float4 acc = make_float4(0.f, 0.f, 0.f, 0.f);
    for (int j0 = start; j0 < end; j0 += 64) {
        int jj = j0 + lane;
        int sv = (jj < end) ? csr_src[jj] : 0;
        int nj = min(64, end - j0);
#pragma unroll 4
        for (int i = 0; i < nj; i += 2) {
            int idx = i + hw;
            int s = __shfl(sv, idx, 64);
            if (idx < nj) {
                float4 hv = h4[(size_t)s * 32 + l32];
                acc.x += hv.x; acc.y += hv.y; acc.z += hv.z; acc.w += hv.w;
            }
        }
    }
    acc.x += __shfl_xor(acc.x, 32, 64);
    acc.y += __shfl_xor(acc.y, 32, 64);
    acc.z += __shfl_xor(acc.z, 32, 64);
    acc.w += __shfl_xor(acc.w, 32, 64);
    if (hw == 0) {
        float wi = dinv_in[n];
        float4 r;
        r.x = acc.x * wi; r.y = acc.y * wi; r.z = acc.z * wi; r.w = acc.w * wi;
        ((float4*)outbuf)[(size_t)row * 32 + l32] = r;
    }
}

// ---------------------------------------------------------------------------
// LDS-free register-blocked matmul:
//   out[r][c] = (sum_k in[r][k]*W[k][c] + b[c]) * (scale ? scale[r] : 1)
// 256 threads, tile = 64 rows x 128 cols; thread = 4 rows x 8 cols.
// W is read from global (L1/L2-resident, shared by all blocks); A rows are
// broadcast loads (4 distinct addresses per wave-instr, L1-served).
// ---------------------------------------------------------------------------

#define MM_FMA_ROW(i, aval, w0, w1)                                                   \
    acc[i][0] = fmaf(aval, w0.x, acc[i][0]); acc[i][1] = fmaf(aval, w0.y, acc[i][1]); \
    acc[i][2] = fmaf(aval, w0.z, acc[i][2]); acc[i][3] = fmaf(aval, w0.w, acc[i][3]); \
    acc[i][4] = fmaf(aval, w1.x, acc[i][4]); acc[i][5] = fmaf(aval, w1.y, acc[i][5]); \
    acc[i][6] = fmaf(aval, w1.z, acc[i][6]); acc[i][7] = fmaf(aval, w1.w, acc[i][7]);

#define MM_K_STEP(kk, comp)                                                           \
    {                                                                                 \
        float4 w0 = W4[(size_t)(k4 + kk) * 32 + tx * 2];                              \
        float4 w1 = W4[(size_t)(k4 + kk) * 32 + tx * 2 + 1];                          \
        MM_FMA_ROW(0, a0.comp, w0, w1)                                                \
        MM_FMA_ROW(1, a1.comp, w0, w1)                                                \
        MM_FMA_ROW(2, a2.comp, w0, w1)                                                \
        MM_FMA_ROW(3, a3.comp, w0, w1)                                                \
    }

__global__ __launch_bounds__(256) void matmul_bias_kernel(
        const float* __restrict__ in, const float* __restrict__ W,
        const float* __restrict__ b, const float* __restrict__ scale,
        float* __restrict__ outbuf, int nrows) {
    int t = threadIdx.x;
    int tx = t & 15, ty = t >> 4;  // 16 x 16
    int r0 = blockIdx.x * 64;
    int rb = r0 + ty * 4;

    const float4* in4 = (const float4*)in;
    const float4* W4 = (const float4*)W;

    // clamped row indices (stores are guarded; loads just need to stay in-bounds)
    int r_0 = min(rb + 0, nrows - 1);
    int r_1 = min(rb + 1, nrows - 1);
    int r_2 = min(rb + 2, nrows - 1);
    int r_3 = min(rb + 3, nrows - 1);

    float4 bv0 = ((const float4*)b)[tx * 2];
    float4 bv1 = ((const float4*)b)[tx * 2 + 1];

    float acc[4][8];
#pragma unroll
    for (int i = 0; i < 4; ++i) {
        acc[i][0] = bv0.x; acc[i][1] = bv0.y; acc[i][2] = bv0.z; acc[i][3] = bv0.w;
        acc[i][4] = bv1.x; acc[i][5] = bv1.y; acc[i][6] = bv1.z; acc[i][7] = bv1.w;
    }

#pragma unroll 2
    for (int kb = 0; kb < 32; ++kb) {
        float4 a0 = in4[(size_t)r_0 * 32 + kb];
        float4 a1 = in4[(size_t)r_1 * 32 + kb];
        float4 a2 = in4[(size_t)r_2 * 32 + kb];
        float4 a3 = in4[(size_t)r_3 * 32 + kb];
        int k4 = kb * 4;
        MM_K_STEP(0, x)
        MM_K_STEP(1, y)
        MM_K_STEP(2, z)
        MM_K_STEP(3, w)
    }

#pragma unroll
    for (int i = 0; i < 4; ++i) {
        int r = rb + i;
        if (r < nrows) {
            float s = scale ? scale[r] : 1.0f;
            float4 o0, o1;
            o0.x = acc[i][0] * s; o0.y = acc[i][1] * s; o0.z = acc[i][2] * s; o0.w = acc[i][3] * s;
            o1.x = acc[i][4] * s; o1.y = acc[i][5] * s; o1.z = acc[i][6] * s; o1.w = acc[i][7] * s;
            float4* op = (float4*)&outbuf[(size_t)r * D + tx * 8];
            op[0] = o0;
            op[1] = o1;
        }
    }
}

// ---------------------------------------------------------------------------

extern "C" void kernel_launch(void* const* d_in, const int* in_sizes, int n_in,
                              void* d_out, int out_size, void* d_ws, size_t ws_size,
                              hipStream_t stream) {
    const int* labels = (const int*)d_in[0];
    const int* src    = (const int*)d_in[1];
    const int* dst    = (const int*)d_in[2];
    const float* feat = (const float*)d_in[3];
    const float* W0   = (const float*)d_in[4];
    const float* b0   = (const float*)d_in[5];
    const float* W1   = (const float*)d_in[6];
    const float* b1   = (const float*)d_in[7];
    const float* W2   = (const float*)d_in[8];
    const float* b2   = (const float*)d_in[9];
    float* out = (float*)d_out;

    char* ws = (char*)d_ws;
    size_t off = 0;
    auto alloc = [&](size_t bytes) -> void* {
        void* p = ws + off;
        off = (off + bytes + 255) & ~(size_t)255;
        return p;
    };
    int* cnt_out   = (int*)alloc(N_NODES * 4);
    int* cnt_in    = (int*)alloc(N_NODES * 4);
    int* row_off   = (int*)alloc((N_NODES + 1) * 4);
    int* cursor    = (int*)alloc(N_NODES * 4);
    int* blocksums = (int*)alloc(256 * 4);
    int* blockoffs = (int*)alloc(256 * 4);
    int* csr_src   = (int*)alloc((size_t)N_EDGES * 4);
    float* dinv_out = (float*)alloc(N_NODES * 4);
    float* dinv_in  = (float*)alloc(N_NODES * 4);
    float* bufA = (float*)alloc((size_t)N_NODES * D * 4);
    float* bufB = (float*)alloc((size_t)N_NODES * D * 4);

    hipMemsetAsync(cnt_out, 0, N_NODES * 4, stream);
    hipMemsetAsync(cnt_in, 0, N_NODES * 4, stream);
    hipMemsetAsync(cursor, 0, N_NODES * 4, stream);

    const int nScanBlocks = (N_NODES + 255) / 256;  // 196

    count_kernel<<<(N_EDGES + 255) / 256, 256, 0, stream>>>(src, dst, cnt_out, cnt_in);
    dinv_kernel<<<nScanBlocks, 256, 0, stream>>>(cnt_out, cnt_in, dinv_out, dinv_in);
    scan_blocks_kernel<<<nScanBlocks, 256, 0, stream>>>(cnt_in, row_off, blocksums);
    scan_top_kernel<<<1, 256, 0, stream>>>(blocksums, blockoffs, nScanBlocks);
    scan_add_kernel<<<nScanBlocks, 256, 0, stream>>>(row_off, blockoffs);
    fill_csr_kernel<<<(N_EDGES + 255) / 256, 256, 0, stream>>>(src, dst, row_off, cursor, csr_src);

    const int aggGridFull = (N_NODES + 3) / 4;
    const int aggGridLbl  = (N_LABELS + 3) / 4;
    const int mmGridFull  = (N_NODES + 63) / 64;  // 782
    const int mmGridLbl   = (N_LABELS + 63) / 64; // 64

    // hs0 = feat * dinv_out  -> bufA
    prescale_kernel<<<(N_NODES * 32 + 255) / 256, 256, 0, stream>>>(feat, dinv_out, bufA);

    // layer 0: agg(bufA) -> bufB ; (bufB@W0+b0)*dinv_out -> bufA
    aggregate_kernel<<<aggGridFull, 256, 0, stream>>>(bufA, csr_src, row_off, dinv_in, bufB,
                                                      nullptr, N_NODES);
    matmul_bias_kernel<<<mmGridFull, 256, 0, stream>>>(bufB, W0, b0, dinv_out, bufA, N_NODES);

    // layer 1
    aggregate_kernel<<<aggGridFull, 256, 0, stream>>>(bufA, csr_src, row_off, dinv_in, bufB,
                                                      nullptr, N_NODES);
    matmul_bias_kernel<<<mmGridFull, 256, 0, stream>>>(bufB, W1, b1, dinv_out, bufA, N_NODES);

    // layer 2: only label rows
    aggregate_kernel<<<aggGridLbl, 256, 0, stream>>>(bufA, csr_src, row_off, dinv_in, bufB,
                                                     labels, N_LABELS);
    matmul_bias_kernel<<<mmGridLbl, 256, 0, stream>>>(bufB, W2, b2, nullptr, out, N_LABELS);
}

// Round 4
// 308.577 us; speedup vs baseline: 1.7538x; 1.2630x over previous
//
#include <hip/hip_runtime.h>

#define N_NODES 50000
#define N_EDGES 800000
#define D 128
#define N_LABELS 4096
#define PAD 16  // counters padded to one per 64B cacheline

// ---------------------------------------------------------------------------
// CSR build: count (padded counters, dst-position capture) -> scan -> scatter
// ---------------------------------------------------------------------------

__global__ void count_kernel(const int* __restrict__ src, const int* __restrict__ dst,
                             int* __restrict__ cnt_out_p, int* __restrict__ cnt_in_p,
                             int* __restrict__ epos) {
    int e = blockIdx.x * 256 + threadIdx.x;
    if (e >= N_EDGES) return;
    atomicAdd(&cnt_out_p[src[e] * PAD], 1);
    epos[e] = atomicAdd(&cnt_in_p[dst[e] * PAD], 1);
}

__global__ void dinv_kernel(const int* __restrict__ cnt_out_p, const int* __restrict__ cnt_in_p,
                            float* __restrict__ dinv_out, float* __restrict__ dinv_in,
                            float* __restrict__ dinv_io) {
    int n = blockIdx.x * 256 + threadIdx.x;
    if (n >= N_NODES) return;
    int co = cnt_out_p[n * PAD], ci = cnt_in_p[n * PAD];
    float do_ = (co > 0) ? 1.0f / sqrtf((float)co) : 0.0f;
    float di_ = (ci > 0) ? 1.0f / sqrtf((float)ci) : 0.0f;
    dinv_out[n] = do_;
    dinv_in[n] = di_;
    dinv_io[n] = do_ * di_;
}

__global__ void scan_blocks_kernel(const int* __restrict__ cnt_p, int* __restrict__ row_off,
                                   int* __restrict__ blocksums) {
    __shared__ int s[256];
    int t = threadIdx.x;
    int i = blockIdx.x * 256 + t;
    int v = (i < N_NODES) ? cnt_p[i * PAD] : 0;
    s[t] = v;
    __syncthreads();
    for (int offs = 1; offs < 256; offs <<= 1) {
        int add = (t >= offs) ? s[t - offs] : 0;
        __syncthreads();
        s[t] += add;
        __syncthreads();
    }
    if (i < N_NODES) row_off[i + 1] = s[t];
    if (t == 255) blocksums[blockIdx.x] = s[255];
}

__global__ void scan_top_kernel(const int* __restrict__ blocksums, int* __restrict__ blockoffs,
                                int nblocks) {
    __shared__ int s[256];
    int t = threadIdx.x;
    int v = (t < nblocks) ? blocksums[t] : 0;
    s[t] = v;
    __syncthreads();
    for (int offs = 1; offs < 256; offs <<= 1) {
        int add = (t >= offs) ? s[t - offs] : 0;
        __syncthreads();
        s[t] += add;
        __syncthreads();
    }
    blockoffs[t] = s[t] - v;  // exclusive
}

__global__ void scan_add_kernel(int* __restrict__ row_off, const int* __restrict__ blockoffs) {
    int i = blockIdx.x * 256 + threadIdx.x;
    if (i < N_NODES) row_off[i + 1] += blockoffs[blockIdx.x];
    if (i == 0) row_off[0] = 0;
}

__global__ void fill_csr_kernel(const int* __restrict__ src, const int* __restrict__ dst,
                                const int* __restrict__ row_off, const int* __restrict__ epos,
                                int* __restrict__ csr_src) {
    int e = blockIdx.x * 256 + threadIdx.x;
    if (e >= N_EDGES) return;
    int d = dst[e];
    csr_src[row_off[d] + epos[e]] = src[e];
}

// ---------------------------------------------------------------------------
// u1 = M*1 ; u1s = dinv_io * (A dinv_out) ; u2 = dinv_in * (A u1s)
// ---------------------------------------------------------------------------

__global__ void u1_kernel(const int* __restrict__ csr_src, const int* __restrict__ row_off,
                          const float* __restrict__ dinv_out, const float* __restrict__ dinv_in,
                          const float* __restrict__ dinv_io,
                          float* __restrict__ u1, float* __restrict__ u1s) {
    int n = blockIdx.x * 256 + threadIdx.x;
    if (n >= N_NODES) return;
    int a = row_off[n], bnd = row_off[n + 1];
    float s = 0.f;
    for (int j = a; j < bnd; ++j) s += dinv_out[csr_src[j]];
    u1[n] = dinv_in[n] * s;
    u1s[n] = dinv_io[n] * s;
}

__global__ void u2_kernel(const int* __restrict__ csr_src, const int* __restrict__ row_off,
                          const float* __restrict__ u1s, const float* __restrict__ dinv_in,
                          float* __restrict__ u2) {
    int n = blockIdx.x * 256 + threadIdx.x;
    if (n >= N_NODES) return;
    int a = row_off[n], bnd = row_off[n + 1];
    float s = 0.f;
    for (int j = a; j < bnd; ++j) s += u1s[csr_src[j]];
    u2[n] = dinv_in[n] * s;
}

__global__ void gatherl_kernel(const int* __restrict__ labels, const float* __restrict__ u1,
                               const float* __restrict__ u2, float* __restrict__ u1l,
                               float* __restrict__ u2l) {
    int i = blockIdx.x * 256 + threadIdx.x;
    if (i >= N_LABELS) return;
    int n = labels[i];
    u1l[i] = u1[n];
    u2l[i] = u2[n];
}

// ---------------------------------------------------------------------------
// prescale: hs = feat * dinv_out[n]
// ---------------------------------------------------------------------------

__global__ void prescale_kernel(const float* __restrict__ feat,
                                const float* __restrict__ dinv_out,
                                float* __restrict__ hs) {
    int i = blockIdx.x * 256 + threadIdx.x;  // float4 index
    if (i >= N_NODES * 32) return;
    int n = i >> 5;
    float s = dinv_out[n];
    float4 v = ((const float4*)feat)[i];
    float4 r;
    r.x = v.x * s; r.y = v.y * s; r.z = v.z * s; r.w = v.w * s;
    ((float4*)hs)[i] = r;
}

// ---------------------------------------------------------------------------
// Pull aggregation: out[row] = scale_vec[n] * sum_{s in N_in(n)} hs[s]
// one wave per row; each half-wave (32 lanes, float4/lane) takes alternate nbrs
// ---------------------------------------------------------------------------

__global__ __launch_bounds__(256) void aggregate_kernel(
        const float* __restrict__ hs, const int* __restrict__ csr_src,
        const int* __restrict__ row_off, const float* __restrict__ scale_vec,
        float* __restrict__ outbuf, const int* __restrict__ nodeidx, int nrows) {
    int wave = threadIdx.x >> 6;
    int lane = threadIdx.x & 63;
    int hw = lane >> 5, l32 = lane & 31;
    int row = blockIdx.x * 4 + wave;
    if (row >= nrows) return;
    int n = nodeidx ? nodeidx[row] : row;
    int start = row_off[n];
    int end = row_off[n + 1];
    const float4* h4 = (const float4*)hs;
    float4 acc = make_float4(0.f, 0.f, 0.f, 0.f);
    for (int j0 = start; j0 < end; j0 += 64) {
        int jj = j0 + lane;
        int sv = (jj < end) ? csr_src[jj] : 0;
        int nj = min(64, end - j0);
#pragma unroll 4
        for (int i = 0; i < nj; i += 2) {
            int idx = i + hw;
            int s = __shfl(sv, idx, 64);
            if (idx < nj) {
                float4 hv = h4[(size_t)s * 32 + l32];
                acc.x += hv.x; acc.y += hv.y; acc.z += hv.z; acc.w += hv.w;
            }
        }
    }
    acc.x += __shfl_xor(acc.x, 32, 64);
    acc.y += __shfl_xor(acc.y, 32, 64);
    acc.z += __shfl_xor(acc.z, 32, 64);
    acc.w += __shfl_xor(acc.w, 32, 64);
    if (hw == 0) {
        float wi = scale_vec[n];
        float4 r;
        r.x = acc.x * wi; r.y = acc.y * wi; r.z = acc.z * wi; r.w = acc.w * wi;
        ((float4*)outbuf)[(size_t)row * 32 + l32] = r;
    }
}

// ---------------------------------------------------------------------------
// Small matmul (4096 rows): out[r][c] = sum_k in[r][k]*W[k][c] + brow[r]*b[c]
// 256 threads/block, tile = 16 rows; thread = 1 row x 8 cols. 256 blocks.
// W & in are L1/L2-resident; no LDS.
// ---------------------------------------------------------------------------

__global__ __launch_bounds__(256) void matmul16_kernel(
        const float* __restrict__ in, const float* __restrict__ W,
        const float* __restrict__ b, const float* __restrict__ brow,
        float* __restrict__ outbuf, int nrows) {
    int t = threadIdx.x;
    int tx = t & 15, ty = t >> 4;  // 16 cols-groups x 16 rows
    int r = blockIdx.x * 16 + ty;
    if (r >= nrows) return;

    const float4* in4 = (const float4*)in;
    const float4* W4 = (const float4*)W;

    float bs = brow ? brow[r] : 1.0f;
    float4 bv0 = ((const float4*)b)[tx * 2];
    float4 bv1 = ((const float4*)b)[tx * 2 + 1];

    float acc[8];
    acc[0] = bs * bv0.x; acc[1] = bs * bv0.y; acc[2] = bs * bv0.z; acc[3] = bs * bv0.w;
    acc[4] = bs * bv1.x; acc[5] = bs * bv1.y; acc[6] = bs * bv1.z; acc[7] = bs * bv1.w;

#pragma unroll 4
    for (int kb = 0; kb < 32; ++kb) {
        float4 a = in4[(size_t)r * 32 + kb];
        int k4 = kb * 4;
#define MM16_STEP(kk, comp)                                           \
        {                                                             \
            float4 w0 = W4[(size_t)(k4 + kk) * 32 + tx * 2];          \
            float4 w1 = W4[(size_t)(k4 + kk) * 32 + tx * 2 + 1];      \
            acc[0] = fmaf(a.comp, w0.x, acc[0]);                      \
            acc[1] = fmaf(a.comp, w0.y, acc[1]);                      \
            acc[2] = fmaf(a.comp, w0.z, acc[2]);                      \
            acc[3] = fmaf(a.comp, w0.w, acc[3]);                      \
            acc[4] = fmaf(a.comp, w1.x, acc[4]);                      \
            acc[5] = fmaf(a.comp, w1.y, acc[5]);                      \
            acc[6] = fmaf(a.comp, w1.z, acc[6]);                      \
            acc[7] = fmaf(a.comp, w1.w, acc[7]);                      \
        }
        MM16_STEP(0, x)
        MM16_STEP(1, y)
        MM16_STEP(2, z)
        MM16_STEP(3, w)
#undef MM16_STEP
    }

    float4 o0, o1;
    o0.x = acc[0]; o0.y = acc[1]; o0.z = acc[2]; o0.w = acc[3];
    o1.x = acc[4]; o1.y = acc[5]; o1.z = acc[6]; o1.w = acc[7];
    float4* op = (float4*)&outbuf[(size_t)r * D + tx * 8];
    op[0] = o0;
    op[1] = o1;
}

// ---------------------------------------------------------------------------

extern "C" void kernel_launch(void* const* d_in, const int* in_sizes, int n_in,
                              void* d_out, int out_size, void* d_ws, size_t ws_size,
                              hipStream_t stream) {
    const int* labels = (const int*)d_in[0];
    const int* src    = (const int*)d_in[1];
    const int* dst    = (const int*)d_in[2];
    const float* feat = (const float*)d_in[3];
    const float* W0   = (const float*)d_in[4];
    const float* b0   = (const float*)d_in[5];
    const float* W1   = (const float*)d_in[6];
    const float* b1   = (const float*)d_in[7];
    const float* W2   = (const float*)d_in[8];
    const float* b2   = (const float*)d_in[9];
    float* out = (float*)d_out;

    char* ws = (char*)d_ws;
    size_t off = 0;
    auto alloc = [&](size_t bytes) -> void* {
        void* p = ws + off;
        off = (off + bytes + 255) & ~(size_t)255;
        return p;
    };
    int* row_off    = (int*)alloc((N_NODES + 1) * 4);
    int* blocksums  = (int*)alloc(256 * 4);
    int* blockoffs  = (int*)alloc(256 * 4);
    int* csr_src    = (int*)alloc((size_t)N_EDGES * 4);
    float* dinv_out = (float*)alloc(N_NODES * 4);
    float* dinv_in  = (float*)alloc(N_NODES * 4);
    float* dinv_io  = (float*)alloc(N_NODES * 4);
    float* u1       = (float*)alloc(N_NODES * 4);
    float* u1s      = (float*)alloc(N_NODES * 4);
    float* u2       = (float*)alloc(N_NODES * 4);
    float* u1l      = (float*)alloc(N_LABELS * 4);
    float* u2l      = (float*)alloc(N_LABELS * 4);
    float* bufA = (float*)alloc((size_t)N_NODES * D * 4);
    float* bufB = (float*)alloc((size_t)N_NODES * D * 4);

    // aliased scratch (dead before first real use of bufA/bufB):
    //  - padded counters live in bufA until scans are done (prescale writes bufA later)
    //  - epos lives in bufB until fill_csr is done (agg1 writes bufB later)
    int* cnt_out_p = (int*)bufA;                          // N_NODES*PAD ints = 3.2 MB
    int* cnt_in_p  = (int*)bufA + (size_t)N_NODES * PAD;  // 3.2 MB
    int* epos      = (int*)bufB;                          // N_EDGES ints = 3.2 MB

    hipMemsetAsync(cnt_out_p, 0, (size_t)N_NODES * PAD * 4, stream);
    hipMemsetAsync(cnt_in_p, 0, (size_t)N_NODES * PAD * 4, stream);

    const int nScanBlocks = (N_NODES + 255) / 256;  // 196

    count_kernel<<<(N_EDGES + 255) / 256, 256, 0, stream>>>(src, dst, cnt_out_p, cnt_in_p, epos);
    dinv_kernel<<<nScanBlocks, 256, 0, stream>>>(cnt_out_p, cnt_in_p, dinv_out, dinv_in, dinv_io);
    scan_blocks_kernel<<<nScanBlocks, 256, 0, stream>>>(cnt_in_p, row_off, blocksums);
    scan_top_kernel<<<1, 256, 0, stream>>>(blocksums, blockoffs, nScanBlocks);
    scan_add_kernel<<<nScanBlocks, 256, 0, stream>>>(row_off, blockoffs);
    fill_csr_kernel<<<(N_EDGES + 255) / 256, 256, 0, stream>>>(src, dst, row_off, epos, csr_src);

    // rank-1 bias-propagation vectors
    u1_kernel<<<nScanBlocks, 256, 0, stream>>>(csr_src, row_off, dinv_out, dinv_in, dinv_io, u1, u1s);
    u2_kernel<<<nScanBlocks, 256, 0, stream>>>(csr_src, row_off, u1s, dinv_in, u2);
    gatherl_kernel<<<(N_LABELS + 255) / 256, 256, 0, stream>>>(labels, u1, u2, u1l, u2l);

    // p0 = feat * dinv_out  -> bufA
    prescale_kernel<<<(N_NODES * 32 + 255) / 256, 256, 0, stream>>>(feat, dinv_out, bufA);

    const int aggGridFull = (N_NODES + 3) / 4;
    const int aggGridLbl  = (N_LABELS + 3) / 4;

    // p1 = Dio * A p0 -> bufB ; p2 = Dio * A p1 -> bufA ; t = Din * (A p2)[labels] -> bufB
    aggregate_kernel<<<aggGridFull, 256, 0, stream>>>(bufA, csr_src, row_off, dinv_io, bufB,
                                                      nullptr, N_NODES);
    aggregate_kernel<<<aggGridFull, 256, 0, stream>>>(bufB, csr_src, row_off, dinv_io, bufA,
                                                      nullptr, N_NODES);
    aggregate_kernel<<<aggGridLbl, 256, 0, stream>>>(bufA, csr_src, row_off, dinv_in, bufB,
                                                     labels, N_LABELS);

    // z1 = t@W0 + u2l*b0 ; z2 = z1@W1 + u1l*b1 ; out = z2@W2 + b2
    const int mmGrid = (N_LABELS + 15) / 16;  // 256 blocks
    float* z1 = bufA;                         // bufA dead after label agg
    float* z2 = bufA + (size_t)N_LABELS * D;
    matmul16_kernel<<<mmGrid, 256, 0, stream>>>(bufB, W0, b0, u2l, z1, N_LABELS);
    matmul16_kernel<<<mmGrid, 256, 0, stream>>>(z1, W1, b1, u1l, z2, N_LABELS);
    matmul16_kernel<<<mmGrid, 256, 0, stream>>>(z2, W2, b2, nullptr, out, N_LABELS);
}

// Round 5
// 283.200 us; speedup vs baseline: 1.9110x; 1.0896x over previous
//
#include <hip/hip_runtime.h>

#define N_NODES 50000
#define N_EDGES 800000
#define D 128
#define N_LABELS 4096
#define HB 256           // histogram blocks
#define HWORDS 12500     // 50000/4 packed u8 counters per block (50 KB LDS)

// ---------------------------------------------------------------------------
// src out-degree histogram: per-block LDS (packed 4 x u8 per u32), no global atomics
// ---------------------------------------------------------------------------

__global__ __launch_bounds__(256) void src_hist_kernel(const int* __restrict__ src,
                                                       unsigned int* __restrict__ Hsrc) {
    __shared__ unsigned int hist[HWORDS];
    int t = threadIdx.x;
    for (int i = t; i < HWORDS; i += 256) hist[i] = 0;
    __syncthreads();
    int base = blockIdx.x * (N_EDGES / HB);
    int end = base + (N_EDGES / HB);
    for (int e = base + t; e < end; e += 256) {
        int n = src[e];
        atomicAdd(&hist[n >> 2], 1u << ((n & 3) * 8));
    }
    __syncthreads();
    unsigned int* outp = Hsrc + (size_t)blockIdx.x * HWORDS;
    for (int i = t; i < HWORDS; i += 256) outp[i] = hist[i];
}

// ---------------------------------------------------------------------------
// dst counts + edge position capture (the only remaining global atomics)
// ---------------------------------------------------------------------------

__global__ void count_kernel(const int* __restrict__ dst, int* __restrict__ cnt_in,
                             int* __restrict__ epos) {
    int e = blockIdx.x * 256 + threadIdx.x;
    if (e >= N_EDGES) return;
    epos[e] = atomicAdd(&cnt_in[dst[e]], 1);
}

// ---------------------------------------------------------------------------
// merge src partials + compute dinv vectors
// ---------------------------------------------------------------------------

__global__ void dinv_kernel(const unsigned int* __restrict__ Hsrc,
                            const int* __restrict__ cnt_in,
                            float* __restrict__ dinv_out, float* __restrict__ dinv_in,
                            float* __restrict__ dinv_io) {
    int n = blockIdx.x * 256 + threadIdx.x;
    if (n >= N_NODES) return;
    int w = n >> 2, sh = (n & 3) * 8;
    unsigned int s = 0;
#pragma unroll 8
    for (int b = 0; b < HB; ++b) s += (Hsrc[(size_t)b * HWORDS + w] >> sh) & 0xFFu;
    int co = (int)s;
    int ci = cnt_in[n];
    float do_ = (co > 0) ? 1.0f / sqrtf((float)co) : 0.0f;
    float di_ = (ci > 0) ? 1.0f / sqrtf((float)ci) : 0.0f;
    dinv_out[n] = do_;
    dinv_in[n] = di_;
    dinv_io[n] = do_ * di_;
}

// ---------------------------------------------------------------------------
// generic block scan (inclusive into out[i+1]; out[0]=0 via scan_add)
// ---------------------------------------------------------------------------

__global__ void scan_blocks_kernel(const int* __restrict__ cnt, int* __restrict__ outv,
                                   int* __restrict__ blocksums) {
    __shared__ int s[256];
    int t = threadIdx.x;
    int i = blockIdx.x * 256 + t;
    int v = (i < N_NODES) ? cnt[i] : 0;
    s[t] = v;
    __syncthreads();
    for (int offs = 1; offs < 256; offs <<= 1) {
        int add = (t >= offs) ? s[t - offs] : 0;
        __syncthreads();
        s[t] += add;
        __syncthreads();
    }
    if (i < N_NODES) outv[i + 1] = s[t];
    if (t == 255) blocksums[blockIdx.x] = s[255];
}

__global__ void scan_top_kernel(const int* __restrict__ blocksums, int* __restrict__ blockoffs,
                                int nblocks) {
    __shared__ int s[256];
    int t = threadIdx.x;
    int v = (t < nblocks) ? blocksums[t] : 0;
    s[t] = v;
    __syncthreads();
    for (int offs = 1; offs < 256; offs <<= 1) {
        int add = (t >= offs) ? s[t - offs] : 0;
        __syncthreads();
        s[t] += add;
        __syncthreads();
    }
    blockoffs[t] = s[t] - v;  // exclusive
}

__global__ void scan_add_kernel(int* __restrict__ outv, const int* __restrict__ blockoffs) {
    int i = blockIdx.x * 256 + threadIdx.x;
    if (i < N_NODES) outv[i + 1] += blockoffs[blockIdx.x];
    if (i == 0) outv[0] = 0;
}

__global__ void fill_csr_kernel(const int* __restrict__ src, const int* __restrict__ dst,
                                const int* __restrict__ row_off, const int* __restrict__ epos,
                                int* __restrict__ csr_src) {
    int e = blockIdx.x * 256 + threadIdx.x;
    if (e >= N_EDGES) return;
    int d = dst[e];
    csr_src[row_off[d] + epos[e]] = src[e];
}

// ---------------------------------------------------------------------------
// bias-propagation vectors: u1 = M*1 ; u1s = dinv_io*(A dinv_out) ; u2 = Din*(A u1s)
// ---------------------------------------------------------------------------

__global__ void u1_kernel(const int* __restrict__ csr_src, const int* __restrict__ row_off,
                          const float* __restrict__ dinv_out, const float* __restrict__ dinv_in,
                          const float* __restrict__ dinv_io,
                          float* __restrict__ u1, float* __restrict__ u1s) {
    int n = blockIdx.x * 256 + threadIdx.x;
    if (n >= N_NODES) return;
    int a = row_off[n], bnd = row_off[n + 1];
    float s = 0.f;
    for (int j = a; j < bnd; ++j) s += dinv_out[csr_src[j]];
    u1[n] = dinv_in[n] * s;
    u1s[n] = dinv_io[n] * s;
}

__global__ void u2_kernel(const int* __restrict__ csr_src, const int* __restrict__ row_off,
                          const float* __restrict__ u1s, const float* __restrict__ dinv_in,
                          float* __restrict__ u2) {
    int n = blockIdx.x * 256 + threadIdx.x;
    if (n >= N_NODES) return;
    int a = row_off[n], bnd = row_off[n + 1];
    float s = 0.f;
    for (int j = a; j < bnd; ++j) s += u1s[csr_src[j]];
    u2[n] = dinv_in[n] * s;
}

__global__ void gatherl_kernel(const int* __restrict__ labels, const float* __restrict__ u1,
                               const float* __restrict__ u2, float* __restrict__ u1l,
                               float* __restrict__ u2l) {
    int i = blockIdx.x * 256 + threadIdx.x;
    if (i >= N_LABELS) return;
    int n = labels[i];
    u1l[i] = u1[n];
    u2l[i] = u2[n];
}

// ---------------------------------------------------------------------------
// active set for agg2: nodes appearing as src of any label-row edge
// ---------------------------------------------------------------------------

__global__ void flag_kernel(const int* __restrict__ labels, const int* __restrict__ row_off,
                            const int* __restrict__ csr_src, int* __restrict__ flag) {
    int i = blockIdx.x * 256 + threadIdx.x;
    if (i >= N_LABELS) return;
    int n = labels[i];
    int a = row_off[n], bnd = row_off[n + 1];
    for (int j = a; j < bnd; ++j) flag[csr_src[j]] = 1;
}

__global__ void compact_kernel(const int* __restrict__ flag, const int* __restrict__ fpos,
                               int* __restrict__ active) {
    int n = blockIdx.x * 256 + threadIdx.x;
    if (n >= N_NODES) return;
    if (flag[n]) active[fpos[n]] = n;
}

// ---------------------------------------------------------------------------
// pull-aggregation row body: acc += w[s] * hs[s] over in-neighbors
// ---------------------------------------------------------------------------

__device__ __forceinline__ void agg_row(const float* __restrict__ hs,
                                        const int* __restrict__ csr_src,
                                        const float* __restrict__ wvec,
                                        int start, int end, int lane, int hw, int l32,
                                        float4& acc) {
    const float4* h4 = (const float4*)hs;
    for (int j0 = start; j0 < end; j0 += 64) {
        int jj = j0 + lane;
        int sv = (jj < end) ? csr_src[jj] : 0;
        float wv = 1.0f;
        if (wvec) wv = (jj < end) ? wvec[sv] : 0.0f;
        int nj = min(64, end - j0);
#pragma unroll 4
        for (int i = 0; i < nj; i += 2) {
            int idx = i + hw;
            int s = __shfl(sv, idx, 64);
            float w = __shfl(wv, idx, 64);
            if (idx < nj) {
                float4 hv = h4[(size_t)s * 32 + l32];
                acc.x = fmaf(w, hv.x, acc.x);
                acc.y = fmaf(w, hv.y, acc.y);
                acc.z = fmaf(w, hv.z, acc.z);
                acc.w = fmaf(w, hv.w, acc.w);
            }
        }
    }
}

// out[row] = scale_vec[n] * sum_{s in Nin(n)} wvec[s]*hs[s],  n = nodeidx?nodeidx[row]:row
__global__ __launch_bounds__(256) void aggregate_kernel(
        const float* __restrict__ hs, const int* __restrict__ csr_src,
        const int* __restrict__ row_off, const float* __restrict__ wvec,
        const float* __restrict__ scale_vec, float* __restrict__ outbuf,
        const int* __restrict__ nodeidx, int nrows) {
    int wave = threadIdx.x >> 6;
    int lane = threadIdx.x & 63;
    int hw = lane >> 5, l32 = lane & 31;
    int row = blockIdx.x * 4 + wave;
    if (row >= nrows) return;
    int n = nodeidx ? nodeidx[row] : row;
    float4 acc = make_float4(0.f, 0.f, 0.f, 0.f);
    agg_row(hs, csr_src, wvec, row_off[n], row_off[n + 1], lane, hw, l32, acc);
    acc.x += __shfl_xor(acc.x, 32, 64);
    acc.y += __shfl_xor(acc.y, 32, 64);
    acc.z += __shfl_xor(acc.z, 32, 64);
    acc.w += __shfl_xor(acc.w, 32, 64);
    if (hw == 0) {
        float wi = scale_vec[n];
        float4 r;
        r.x = acc.x * wi; r.y = acc.y * wi; r.z = acc.z * wi; r.w = acc.w * wi;
        ((float4*)outbuf)[(size_t)row * 32 + l32] = r;
    }
}

// active-list variant: out row index = node id (write-by-node)
__global__ __launch_bounds__(256) void aggregate_active_kernel(
        const float* __restrict__ hs, const int* __restrict__ csr_src,
        const int* __restrict__ row_off, const float* __restrict__ scale_vec,
        float* __restrict__ outbuf, const int* __restrict__ active,
        const int* __restrict__ nact) {
    int wave = threadIdx.x >> 6;
    int lane = threadIdx.x & 63;
    int hw = lane >> 5, l32 = lane & 31;
    int row = blockIdx.x * 4 + wave;
    if (row >= *nact) return;
    int n = active[row];
    float4 acc = make_float4(0.f, 0.f, 0.f, 0.f);
    agg_row(hs, csr_src, nullptr, row_off[n], row_off[n + 1], lane, hw, l32, acc);
    acc.x += __shfl_xor(acc.x, 32, 64);
    acc.y += __shfl_xor(acc.y, 32, 64);
    acc.z += __shfl_xor(acc.z, 32, 64);
    acc.w += __shfl_xor(acc.w, 32, 64);
    if (hw == 0) {
        float wi = scale_vec[n];
        float4 r;
        r.x = acc.x * wi; r.y = acc.y * wi; r.z = acc.z * wi; r.w = acc.w * wi;
        ((float4*)outbuf)[(size_t)n * 32 + l32] = r;
    }
}

// ---------------------------------------------------------------------------
// Small matmul (4096 rows): out[r][c] = sum_k in[r][k]*W[k][c] + brow[r]*b[c]
// ---------------------------------------------------------------------------

__global__ __launch_bounds__(256) void matmul16_kernel(
        const float* __restrict__ in, const float* __restrict__ W,
        const float* __restrict__ b, const float* __restrict__ brow,
        float* __restrict__ outbuf, int nrows) {
    int t = threadIdx.x;
    int tx = t & 15, ty = t >> 4;
    int r = blockIdx.x * 16 + ty;
    if (r >= nrows) return;

    const float4* in4 = (const float4*)in;
    const float4* W4 = (const float4*)W;

    float bs = brow ? brow[r] : 1.0f;
    float4 bv0 = ((const float4*)b)[tx * 2];
    float4 bv1 = ((const float4*)b)[tx * 2 + 1];

    float acc[8];
    acc[0] = bs * bv0.x; acc[1] = bs * bv0.y; acc[2] = bs * bv0.z; acc[3] = bs * bv0.w;
    acc[4] = bs * bv1.x; acc[5] = bs * bv1.y; acc[6] = bs * bv1.z; acc[7] = bs * bv1.w;

#pragma unroll 4
    for (int kb = 0; kb < 32; ++kb) {
        float4 a = in4[(size_t)r * 32 + kb];
        int k4 = kb * 4;
#define MM16_STEP(kk, comp)                                           \
        {                                                             \
            float4 w0 = W4[(size_t)(k4 + kk) * 32 + tx * 2];          \
            float4 w1 = W4[(size_t)(k4 + kk) * 32 + tx * 2 + 1];      \
            acc[0] = fmaf(a.comp, w0.x, acc[0]);                      \
            acc[1] = fmaf(a.comp, w0.y, acc[1]);                      \
            acc[2] = fmaf(a.comp, w0.z, acc[2]);                      \
            acc[3] = fmaf(a.comp, w0.w, acc[3]);                      \
            acc[4] = fmaf(a.comp, w1.x, acc[4]);                      \
            acc[5] = fmaf(a.comp, w1.y, acc[5]);                      \
            acc[6] = fmaf(a.comp, w1.z, acc[6]);                      \
            acc[7] = fmaf(a.comp, w1.w, acc[7]);                      \
        }
        MM16_STEP(0, x)
        MM16_STEP(1, y)
        MM16_STEP(2, z)
        MM16_STEP(3, w)
#undef MM16_STEP
    }

    float4 o0, o1;
    o0.x = acc[0]; o0.y = acc[1]; o0.z = acc[2]; o0.w = acc[3];
    o1.x = acc[4]; o1.y = acc[5]; o1.z = acc[6]; o1.w = acc[7];
    float4* op = (float4*)&outbuf[(size_t)r * D + tx * 8];
    op[0] = o0;
    op[1] = o1;
}

// ---------------------------------------------------------------------------

extern "C" void kernel_launch(void* const* d_in, const int* in_sizes, int n_in,
                              void* d_out, int out_size, void* d_ws, size_t ws_size,
                              hipStream_t stream) {
    const int* labels = (const int*)d_in[0];
    const int* src    = (const int*)d_in[1];
    const int* dst    = (const int*)d_in[2];
    const float* feat = (const float*)d_in[3];
    const float* W0   = (const float*)d_in[4];
    const float* b0   = (const float*)d_in[5];
    const float* W1   = (const float*)d_in[6];
    const float* b1   = (const float*)d_in[7];
    const float* W2   = (const float*)d_in[8];
    const float* b2   = (const float*)d_in[9];
    float* out = (float*)d_out;

    char* ws = (char*)d_ws;
    size_t off = 0;
    auto alloc = [&](size_t bytes) -> void* {
        void* p = ws + off;
        off = (off + bytes + 255) & ~(size_t)255;
        return p;
    };
    int* row_off    = (int*)alloc((N_NODES + 1) * 4);
    int* fpos       = (int*)alloc((N_NODES + 1) * 4);
    int* blocksums  = (int*)alloc(256 * 4);
    int* blockoffs  = (int*)alloc(256 * 4);
    int* csr_src    = (int*)alloc((size_t)N_EDGES * 4);
    int* cnt_in     = (int*)alloc(N_NODES * 4);
    int* flag       = (int*)alloc(N_NODES * 4);
    int* active     = (int*)alloc(N_NODES * 4);
    float* dinv_out = (float*)alloc(N_NODES * 4);
    float* dinv_in  = (float*)alloc(N_NODES * 4);
    float* dinv_io  = (float*)alloc(N_NODES * 4);
    float* u1       = (float*)alloc(N_NODES * 4);
    float* u1s      = (float*)alloc(N_NODES * 4);
    float* u2       = (float*)alloc(N_NODES * 4);
    float* u1l      = (float*)alloc(N_LABELS * 4);
    float* u2l      = (float*)alloc(N_LABELS * 4);
    float* bufA = (float*)alloc((size_t)N_NODES * D * 4);
    float* bufB = (float*)alloc((size_t)N_NODES * D * 4);

    // aliased scratch (dead before first real use of bufA/bufB):
    unsigned int* Hsrc = (unsigned int*)bufA;  // 256*12500*4 = 12.8 MB, dead after dinv
    int* epos = (int*)bufB;                    // 3.2 MB, dead after fill_csr
    // tail-phase aliases in bufA (p1 dead after agg2):
    float* tbuf = bufA;                                 // 4096*128*4 = 2 MB
    float* z1   = bufA + (size_t)N_LABELS * D;          // 2 MB
    float* z2   = bufA + (size_t)2 * N_LABELS * D;      // 2 MB

    hipMemsetAsync(cnt_in, 0, N_NODES * 4, stream);
    hipMemsetAsync(flag, 0, N_NODES * 4, stream);

    const int nScanBlocks = (N_NODES + 255) / 256;  // 196

    src_hist_kernel<<<HB, 256, 0, stream>>>(src, Hsrc);
    count_kernel<<<(N_EDGES + 255) / 256, 256, 0, stream>>>(dst, cnt_in, epos);
    dinv_kernel<<<nScanBlocks, 256, 0, stream>>>(Hsrc, cnt_in, dinv_out, dinv_in, dinv_io);
    scan_blocks_kernel<<<nScanBlocks, 256, 0, stream>>>(cnt_in, row_off, blocksums);
    scan_top_kernel<<<1, 256, 0, stream>>>(blocksums, blockoffs, nScanBlocks);
    scan_add_kernel<<<nScanBlocks, 256, 0, stream>>>(row_off, blockoffs);
    fill_csr_kernel<<<(N_EDGES + 255) / 256, 256, 0, stream>>>(src, dst, row_off, epos, csr_src);

    // bias-propagation vectors
    u1_kernel<<<nScanBlocks, 256, 0, stream>>>(csr_src, row_off, dinv_out, dinv_in, dinv_io, u1, u1s);
    u2_kernel<<<nScanBlocks, 256, 0, stream>>>(csr_src, row_off, u1s, dinv_in, u2);
    gatherl_kernel<<<(N_LABELS + 255) / 256, 256, 0, stream>>>(labels, u1, u2, u1l, u2l);

    // active set = srcs of label-row edges (what agg3 will gather)
    flag_kernel<<<(N_LABELS + 255) / 256, 256, 0, stream>>>(labels, row_off, csr_src, flag);
    scan_blocks_kernel<<<nScanBlocks, 256, 0, stream>>>(flag, fpos, blocksums);
    scan_top_kernel<<<1, 256, 0, stream>>>(blocksums, blockoffs, nScanBlocks);
    scan_add_kernel<<<nScanBlocks, 256, 0, stream>>>(fpos, blockoffs);
    compact_kernel<<<nScanBlocks, 256, 0, stream>>>(flag, fpos, active);

    const int aggGridFull = (N_NODES + 3) / 4;
    const int aggGridLbl  = (N_LABELS + 3) / 4;

    // p1 = Dio A Dout feat -> bufA (prescale fused via per-neighbor weight)
    aggregate_kernel<<<aggGridFull, 256, 0, stream>>>(feat, csr_src, row_off, dinv_out,
                                                      dinv_io, bufA, nullptr, N_NODES);
    // p2 = Dio A p1 -> bufB, active rows only (write-by-node)
    aggregate_active_kernel<<<aggGridFull, 256, 0, stream>>>(bufA, csr_src, row_off, dinv_io,
                                                             bufB, active, &fpos[N_NODES]);
    // t = Din (A p2)[labels] -> tbuf
    aggregate_kernel<<<aggGridLbl, 256, 0, stream>>>(bufB, csr_src, row_off, nullptr,
                                                     dinv_in, tbuf, labels, N_LABELS);

    // z1 = t@W0 + u2l*b0 ; z2 = z1@W1 + u1l*b1 ; out = z2@W2 + b2
    const int mmGrid = (N_LABELS + 15) / 16;  // 256 blocks
    matmul16_kernel<<<mmGrid, 256, 0, stream>>>(tbuf, W0, b0, u2l, z1, N_LABELS);
    matmul16_kernel<<<mmGrid, 256, 0, stream>>>(z1, W1, b1, u1l, z2, N_LABELS);
    matmul16_kernel<<<mmGrid, 256, 0, stream>>>(z2, W2, b2, nullptr, out, N_LABELS);
}